// Round 9
// baseline (44.904 us; speedup 1.0000x reference)
//
#include <hip/hip_runtime.h>
#include <math.h>

#define NB 2048
#define ND 784
#define NK 128
#define KP 2400            // padded GEMM K: 3*784=2352 -> 2400 = 32*75
#define NSTEP 75           // KP/32 k-steps
#define KSPLIT 5           // K-chunks -> partials
#define SPK 15             // k-steps per chunk
#define MT 128             // M-tile rows per k_mm block (4 waves x 32 rows)

typedef __attribute__((ext_vector_type(8))) short short8;
typedef __attribute__((ext_vector_type(4))) float f32x4;

// ws float offsets:
#define OFF_LW   0
#define OFF_PART 128
#define N_PART   (KSPLIT * NB * NK)          // 1,310,720
#define OFF_AH   (OFF_PART + N_PART)
#define N_A_F    (NB * KP / 2)               // 2,457,600 float slots
#define OFF_AL   (OFF_AH + N_A_F)
#define OFF_BH   (OFF_AL + N_A_F)
#define N_B_F    (NSTEP * 8 * 64 * 8 / 2)    // 153,600 float slots
#define OFF_BL   (OFF_BH + N_B_F)
// total ~6.53M floats ~= 26.1 MB

__device__ inline ushort f2bf(float f) {     // round-to-nearest-even f32->bf16
  uint u = __float_as_uint(f);
  return (ushort)((u + 0x7FFFu + ((u >> 16) & 1u)) >> 16);
}

// Fused prep. Blocks [0,150): B tables (bf16 hi/lo, fragment-linear).
// Blocks [150,1750): A matrix (bf16 hi/lo, row-major [NB][KP]).
__global__ __launch_bounds__(256) void k_prep(
    const float* __restrict__ w, const float* __restrict__ mu,
    const float* __restrict__ cov, const float* __restrict__ data,
    const float* __restrict__ mask, float* __restrict__ ws) {
  if (blockIdx.x < 150) {
    // ---- B-prep: fragment fid = ks*8 + nt; lane l holds
    // B[K = ks*32 + (l>>4)*8 + j][n = nt*16 + (l&15)], j=0..7.
    int tid = blockIdx.x * 256 + threadIdx.x;   // 0..38399
    if (tid < NK) ws[OFF_LW + tid] = logf(w[tid]);
    int l   = tid & 63;
    int fid = tid >> 6;          // 0..599
    int nt  = fid & 7;
    int ks  = fid >> 3;          // 0..74
    int n   = nt * 16 + (l & 15);
    int K0  = ks * 32 + ((l >> 4) << 3);
    ushort hi[8], lo[8];
#pragma unroll
    for (int j = 0; j < 8; j++) {
      int K = K0 + j;
      float v = 0.f;
      if (K < 3 * ND) {
        int d = K / 3;
        int c = K - 3 * d;
        float cv = cov[n * ND + d];
        float mv = mu[n * ND + d];
        v = (c == 0) ? (-0.5f / cv)
          : (c == 1) ? (mv / cv)
                     : (-mv * mv * 0.5f / cv - 0.5f * logf(cv));
      }
      ushort h = f2bf(v);
      hi[j] = h;
      lo[j] = f2bf(v - __uint_as_float(((uint)h) << 16));
    }
    uint4 vh, vl;
    vh.x = (uint)hi[0] | ((uint)hi[1] << 16);
    vh.y = (uint)hi[2] | ((uint)hi[3] << 16);
    vh.z = (uint)hi[4] | ((uint)hi[5] << 16);
    vh.w = (uint)hi[6] | ((uint)hi[7] << 16);
    vl.x = (uint)lo[0] | ((uint)lo[1] << 16);
    vl.y = (uint)lo[2] | ((uint)lo[3] << 16);
    vl.z = (uint)lo[4] | ((uint)lo[5] << 16);
    vl.w = (uint)lo[6] | ((uint)lo[7] << 16);
    ((uint4*)(ws + OFF_BH))[fid * 64 + l] = vh;
    ((uint4*)(ws + OFF_BL))[fid * 64 + l] = vl;
  } else {
    // ---- A-prep: K = 12*dq + 3*dd + c, vals {m*x^2, m*x, m}; dq>=196 -> 0.
    int tid = (blockIdx.x - 150) * 256 + threadIdx.x;   // 0..409599
    int b  = tid / 200;
    int dq = tid - b * 200;
    float vals[12];
    if (dq < 196) {
      float4 x = *(const float4*)(data + (size_t)b * ND + 4 * dq);
      float4 m = *(const float4*)(mask + (size_t)b * ND + 4 * dq);
      float xs[4] = {x.x, x.y, x.z, x.w};
      float ms[4] = {m.x, m.y, m.z, m.w};
#pragma unroll
      for (int dd = 0; dd < 4; dd++) {
        float mm = ms[dd], xx = xs[dd];
        float mx = mm * xx;
        vals[3 * dd]     = mx * xx;
        vals[3 * dd + 1] = mx;
        vals[3 * dd + 2] = mm;
      }
    } else {
#pragma unroll
      for (int i = 0; i < 12; i++) vals[i] = 0.f;
    }
    uint ah[6], al[6];
#pragma unroll
    for (int i = 0; i < 6; i++) {
      ushort h0 = f2bf(vals[2 * i]), h1 = f2bf(vals[2 * i + 1]);
      float r0 = vals[2 * i]     - __uint_as_float(((uint)h0) << 16);
      float r1 = vals[2 * i + 1] - __uint_as_float(((uint)h1) << 16);
      ushort l0 = f2bf(r0), l1 = f2bf(r1);
      ah[i] = (uint)h0 | ((uint)h1 << 16);
      al[i] = (uint)l0 | ((uint)l1 << 16);
    }
    uint* Ahu = (uint*)(ws + OFF_AH) + (size_t)b * (KP / 2) + 6 * dq;
    uint* Alu = (uint*)(ws + OFF_AL) + (size_t)b * (KP / 2) + 6 * dq;
#pragma unroll
    for (int i = 0; i < 3; i++) {
      ((uint2*)Ahu)[i] = make_uint2(ah[2 * i], ah[2 * i + 1]);
      ((uint2*)Alu)[i] = make_uint2(al[2 * i], al[2 * i + 1]);
    }
  }
}

// GEMM: grid = 16 M-tiles x KSPLIT = 80 blocks, 4 waves each.
// Wave w owns rows mt*128 + w*32 .. +31 (2 row-groups of 16), all 128 cols,
// K-chunk of SPK k-steps. No LDS, no barriers. B fragments shared between the
// two row-groups (halves B traffic vs 16-row waves).
// acc layout (m89): col = lane&15, row = (lane>>4)*4 + reg.
__global__ __launch_bounds__(256) void k_mm(float* __restrict__ ws) {
  const ushort* Ah = (const ushort*)(ws + OFF_AH);
  const ushort* Al = (const ushort*)(ws + OFF_AL);
  const short8* Bh = (const short8*)(ws + OFF_BH);
  const short8* Bl = (const short8*)(ws + OFF_BL);
  float* part = ws + OFF_PART;

  int mt = blockIdx.x / KSPLIT;
  int kc = blockIdx.x % KSPLIT;
  int w  = threadIdx.x >> 6;
  int l  = threadIdx.x & 63;
  int r0 = mt * MT + w * 32;
  int rowA = r0 + (l & 15);

  f32x4 acc[2][8];
#pragma unroll
  for (int g = 0; g < 2; g++)
#pragma unroll
    for (int i = 0; i < 8; i++) acc[g][i] = (f32x4){0.f, 0.f, 0.f, 0.f};

  const ushort* pAh0 = Ah + (size_t)rowA * KP + ((l >> 4) << 3);
  const ushort* pAl0 = Al + (size_t)rowA * KP + ((l >> 4) << 3);
  const ushort* pAh1 = pAh0 + 16 * KP;
  const ushort* pAl1 = pAl0 + 16 * KP;

#pragma unroll 3
  for (int s = 0; s < SPK; s++) {
    int ks = kc * SPK + s;
    short8 a0h = *(const short8*)(pAh0 + ks * 32);
    short8 a0l = *(const short8*)(pAl0 + ks * 32);
    short8 a1h = *(const short8*)(pAh1 + ks * 32);
    short8 a1l = *(const short8*)(pAl1 + ks * 32);
    const short8* bh = Bh + (size_t)(ks * 8) * 64 + l;
    const short8* bl = Bl + (size_t)(ks * 8) * 64 + l;
#pragma unroll
    for (int nt = 0; nt < 8; nt++) {
      short8 b_h = bh[nt * 64];
      short8 b_l = bl[nt * 64];
      acc[0][nt] = __builtin_amdgcn_mfma_f32_16x16x32_bf16(a0h, b_h, acc[0][nt], 0, 0, 0);
      acc[0][nt] = __builtin_amdgcn_mfma_f32_16x16x32_bf16(a0h, b_l, acc[0][nt], 0, 0, 0);
      acc[0][nt] = __builtin_amdgcn_mfma_f32_16x16x32_bf16(a0l, b_h, acc[0][nt], 0, 0, 0);
      acc[1][nt] = __builtin_amdgcn_mfma_f32_16x16x32_bf16(a1h, b_h, acc[1][nt], 0, 0, 0);
      acc[1][nt] = __builtin_amdgcn_mfma_f32_16x16x32_bf16(a1h, b_l, acc[1][nt], 0, 0, 0);
      acc[1][nt] = __builtin_amdgcn_mfma_f32_16x16x32_bf16(a1l, b_h, acc[1][nt], 0, 0, 0);
    }
  }

#pragma unroll
  for (int g = 0; g < 2; g++)
#pragma unroll
    for (int nt = 0; nt < 8; nt++)
#pragma unroll
      for (int r = 0; r < 4; r++) {
        int grow = r0 + g * 16 + ((l >> 4) << 2) + r;
        part[((size_t)kc * NB + grow) * NK + nt * 16 + (l & 15)] = acc[g][nt][r];
      }
}

// 2 rows per wave, float4 per lane (k-quad). Reduce KSPLIT partials, +log w,
// NaN fix, LSE with the reference's per-term +1e-8 (4e-8 per lane), exp.
__global__ __launch_bounds__(256) void k_final(
    const float* __restrict__ ws, float* __restrict__ out) {
  const float4* lw4   = (const float4*)(ws + OFF_LW);
  const float4* part4 = (const float4*)(ws + OFF_PART);
  int lane = threadIdx.x & 63;
  int wv   = threadIdx.x >> 6;
  int half = lane >> 5;
  int lk   = lane & 31;
  int b = blockIdx.x * 8 + wv * 2 + half;

  float4 s = make_float4(0.f, 0.f, 0.f, 0.f);
#pragma unroll
  for (int sp = 0; sp < KSPLIT; sp++) {
    float4 v = part4[((size_t)sp * NB + b) * 32 + lk];
    s.x += v.x; s.y += v.y; s.z += v.z; s.w += v.w;
  }
  float4 lv = lw4[lk];
  s.x += lv.x; s.y += lv.y; s.z += lv.z; s.w += lv.w;
  if (isnan(s.x)) s.x = 0.f;
  if (isnan(s.y)) s.y = 0.f;
  if (isnan(s.z)) s.z = 0.f;
  if (isnan(s.w)) s.w = 0.f;

  float mx = fmaxf(fmaxf(s.x, s.y), fmaxf(s.z, s.w));
#pragma unroll
  for (int off = 16; off; off >>= 1) mx = fmaxf(mx, __shfl_xor(mx, off));
  float sum = expf(s.x - mx) + expf(s.y - mx) + expf(s.z - mx) + expf(s.w - mx) + 4e-8f;
#pragma unroll
  for (int off = 16; off; off >>= 1) sum += __shfl_xor(sum, off);
  float lse = logf(sum) + mx;
  float4 o = make_float4(expf(s.x - lse), expf(s.y - lse),
                         expf(s.z - lse), expf(s.w - lse));
  ((float4*)out)[(size_t)b * 32 + lk] = o;
}

extern "C" void kernel_launch(void* const* d_in, const int* in_sizes, int n_in,
                              void* d_out, int out_size, void* d_ws, size_t ws_size,
                              hipStream_t stream) {
  const float* data = (const float*)d_in[0];
  const float* mask = (const float*)d_in[1];
  const float* wts  = (const float*)d_in[2];
  const float* mu   = (const float*)d_in[3];
  const float* cov  = (const float*)d_in[4];
  float* ws  = (float*)d_ws;
  float* out = (float*)d_out;

  k_prep<<<1750, 256, 0, stream>>>(wts, mu, cov, data, mask, ws);
  k_mm<<<16 * KSPLIT, 256, 0, stream>>>(ws);
  k_final<<<NB / 8, 256, 0, stream>>>(ws, out);
}

// Round 10
// 35.779 us; speedup vs baseline: 1.2550x; 1.2550x over previous
//
#include <hip/hip_runtime.h>
#include <math.h>

#define NB 2048
#define ND 784
#define NK 128
#define KP 3136            // 4*784: K = 4d+c, A slots {m*x^2, m*x, m, 0}
#define NSTEP 98           // KP/32 k-steps
#define KSPLIT 14          // K-chunks -> partials
#define SPK 7              // k-steps per chunk
#define MT 64              // rows per k_mm block (4 waves x 16 rows)

typedef __attribute__((ext_vector_type(8))) short short8;
typedef __attribute__((ext_vector_type(4))) float f32x4;

// ws float offsets:
#define OFF_LW   0
#define OFF_PART 128
#define N_PART   (KSPLIT * NB * NK)       // 3,670,016 floats (14.7 MB)
#define OFF_BH   (OFF_PART + N_PART)
#define N_B_F    (NSTEP * 8 * 64 * 4)     // 200,704 float slots per table
#define OFF_BL   (OFF_BH + N_B_F)
// total ~4.07M floats ~= 16.3 MB

__device__ inline ushort f2bf(float f) {   // round-to-nearest-even f32->bf16
  uint u = __float_as_uint(f);
  return (ushort)((u + 0x7FFFu + ((u >> 16) & 1u)) >> 16);
}

// B-prep + log w. Fragment fid = ks*8 + nt; lane l holds
// B[K = ks*32 + (l>>4)*8 + j][n = nt*16 + (l&15)], j=0..7, K = 4d+c:
// c==0 -> -1/2c, c==1 -> mu/c, c==2 -> -mu^2/2c - ln(c)/2, c==3 -> 0.
__global__ __launch_bounds__(256) void k_prep(
    const float* __restrict__ w, const float* __restrict__ mu,
    const float* __restrict__ cov, float* __restrict__ ws) {
  int tid = blockIdx.x * 256 + threadIdx.x;   // 0..50175
  if (tid < NK) ws[OFF_LW + tid] = logf(w[tid]);
  int l   = tid & 63;
  int fid = tid >> 6;          // 0..783
  int nt  = fid & 7;
  int ks  = fid >> 3;          // 0..97
  int n   = nt * 16 + (l & 15);
  int K0  = ks * 32 + ((l >> 4) << 3);
  ushort hi[8], lo[8];
#pragma unroll
  for (int j = 0; j < 8; j++) {
    int K = K0 + j;
    int d = K >> 2;
    int c = K & 3;
    float cv = cov[n * ND + d];
    float mv = mu[n * ND + d];
    float v = (c == 0) ? (-0.5f / cv)
            : (c == 1) ? (mv / cv)
            : (c == 2) ? (-mv * mv * 0.5f / cv - 0.5f * logf(cv))
                       : 0.f;
    ushort h = f2bf(v);
    hi[j] = h;
    lo[j] = f2bf(v - __uint_as_float(((uint)h) << 16));
  }
  uint4 vh, vl;
  vh.x = (uint)hi[0] | ((uint)hi[1] << 16);
  vh.y = (uint)hi[2] | ((uint)hi[3] << 16);
  vh.z = (uint)hi[4] | ((uint)hi[5] << 16);
  vh.w = (uint)hi[6] | ((uint)hi[7] << 16);
  vl.x = (uint)lo[0] | ((uint)lo[1] << 16);
  vl.y = (uint)lo[2] | ((uint)lo[3] << 16);
  vl.z = (uint)lo[4] | ((uint)lo[5] << 16);
  vl.w = (uint)lo[6] | ((uint)lo[7] << 16);
  ((uint4*)(ws + OFF_BH))[fid * 64 + l] = vh;
  ((uint4*)(ws + OFF_BL))[fid * 64 + l] = vl;
}

// GEMM with fused A-conversion: grid = 32 M-tiles x KSPLIT = 448 blocks,
// 4 waves. Wave owns 16 rows x 128 cols x SPK k-steps. Lane l: row r0+(l&15),
// dims d0 = ks*8 + (l>>4)*2 -> float2 of data/mask -> bf16 hi/lo A-fragment
// in registers (m exact in bf16; missing Al*Bl term ~2^-18, validated R8).
// acc layout (m89): col = lane&15, row = (lane>>4)*4 + reg.
__global__ __launch_bounds__(256) void k_mm(
    const float* __restrict__ data, const float* __restrict__ mask,
    float* __restrict__ ws) {
  const short8* Bh = (const short8*)(ws + OFF_BH);
  const short8* Bl = (const short8*)(ws + OFF_BL);
  float* part = ws + OFF_PART;

  int mt = blockIdx.x / KSPLIT;
  int kc = blockIdx.x % KSPLIT;
  int w  = threadIdx.x >> 6;
  int l  = threadIdx.x & 63;
  int r0 = mt * MT + w * 16;
  int rowA = r0 + (l & 15);
  int g2   = (l >> 4) << 1;     // dim offset within k-step: 0,2,4,6

  f32x4 acc[8];
#pragma unroll
  for (int i = 0; i < 8; i++) acc[i] = (f32x4){0.f, 0.f, 0.f, 0.f};

  const float* dp = data + (size_t)rowA * ND + g2;
  const float* mp = mask + (size_t)rowA * ND + g2;

#pragma unroll
  for (int s = 0; s < SPK; s++) {
    int ks = kc * SPK + s;
    float2 x = *(const float2*)(dp + ks * 8);
    float2 m = *(const float2*)(mp + ks * 8);

    float mx0 = m.x * x.x, mq0 = mx0 * x.x;
    float mx1 = m.y * x.y, mq1 = mx1 * x.y;
    ushort h_q0 = f2bf(mq0), h_x0 = f2bf(mx0);
    ushort h_q1 = f2bf(mq1), h_x1 = f2bf(mx1);
    ushort h_m0 = (ushort)(__float_as_uint(m.x) >> 16);  // exact: m in {0,1}
    ushort h_m1 = (ushort)(__float_as_uint(m.y) >> 16);
    float r_q0 = mq0 - __uint_as_float(((uint)h_q0) << 16);
    float r_x0 = mx0 - __uint_as_float(((uint)h_x0) << 16);
    float r_q1 = mq1 - __uint_as_float(((uint)h_q1) << 16);
    float r_x1 = mx1 - __uint_as_float(((uint)h_x1) << 16);

    short8 a_h, a_l;
    a_h[0] = (short)h_q0;       a_h[1] = (short)h_x0;
    a_h[2] = (short)h_m0;       a_h[3] = 0;
    a_h[4] = (short)h_q1;       a_h[5] = (short)h_x1;
    a_h[6] = (short)h_m1;       a_h[7] = 0;
    a_l[0] = (short)f2bf(r_q0); a_l[1] = (short)f2bf(r_x0);
    a_l[2] = 0;                 a_l[3] = 0;
    a_l[4] = (short)f2bf(r_q1); a_l[5] = (short)f2bf(r_x1);
    a_l[6] = 0;                 a_l[7] = 0;

    const short8* bh = Bh + (size_t)(ks * 8) * 64 + l;
    const short8* bl = Bl + (size_t)(ks * 8) * 64 + l;
#pragma unroll
    for (int nt = 0; nt < 8; nt++) {
      short8 b_h = bh[nt * 64];
      short8 b_l = bl[nt * 64];
      acc[nt] = __builtin_amdgcn_mfma_f32_16x16x32_bf16(a_h, b_h, acc[nt], 0, 0, 0);
      acc[nt] = __builtin_amdgcn_mfma_f32_16x16x32_bf16(a_h, b_l, acc[nt], 0, 0, 0);
      acc[nt] = __builtin_amdgcn_mfma_f32_16x16x32_bf16(a_l, b_h, acc[nt], 0, 0, 0);
    }
  }

#pragma unroll
  for (int nt = 0; nt < 8; nt++)
#pragma unroll
    for (int r = 0; r < 4; r++) {
      int grow = r0 + ((l >> 4) << 2) + r;
      part[((size_t)kc * NB + grow) * NK + nt * 16 + (l & 15)] = acc[nt][r];
    }
}

// 2 rows per wave, float4 per lane (k-quad). Reduce KSPLIT partials, +log w,
// NaN fix, LSE with the reference's per-term +1e-8 (4e-8 per lane), exp.
__global__ __launch_bounds__(256) void k_final(
    const float* __restrict__ ws, float* __restrict__ out) {
  const float4* lw4   = (const float4*)(ws + OFF_LW);
  const float4* part4 = (const float4*)(ws + OFF_PART);
  int lane = threadIdx.x & 63;
  int wv   = threadIdx.x >> 6;
  int half = lane >> 5;
  int lk   = lane & 31;
  int b = blockIdx.x * 8 + wv * 2 + half;

  float4 s = make_float4(0.f, 0.f, 0.f, 0.f);
#pragma unroll
  for (int sp = 0; sp < KSPLIT; sp++) {
    float4 v = part4[((size_t)sp * NB + b) * 32 + lk];
    s.x += v.x; s.y += v.y; s.z += v.z; s.w += v.w;
  }
  float4 lv = lw4[lk];
  s.x += lv.x; s.y += lv.y; s.z += lv.z; s.w += lv.w;
  if (isnan(s.x)) s.x = 0.f;
  if (isnan(s.y)) s.y = 0.f;
  if (isnan(s.z)) s.z = 0.f;
  if (isnan(s.w)) s.w = 0.f;

  float mx = fmaxf(fmaxf(s.x, s.y), fmaxf(s.z, s.w));
#pragma unroll
  for (int off = 16; off; off >>= 1) mx = fmaxf(mx, __shfl_xor(mx, off));
  float sum = expf(s.x - mx) + expf(s.y - mx) + expf(s.z - mx) + expf(s.w - mx) + 4e-8f;
#pragma unroll
  for (int off = 16; off; off >>= 1) sum += __shfl_xor(sum, off);
  float lse = logf(sum) + mx;
  float4 o = make_float4(expf(s.x - lse), expf(s.y - lse),
                         expf(s.z - lse), expf(s.w - lse));
  ((float4*)out)[(size_t)b * 32 + lk] = o;
}

extern "C" void kernel_launch(void* const* d_in, const int* in_sizes, int n_in,
                              void* d_out, int out_size, void* d_ws, size_t ws_size,
                              hipStream_t stream) {
  const float* data = (const float*)d_in[0];
  const float* mask = (const float*)d_in[1];
  const float* wts  = (const float*)d_in[2];
  const float* mu   = (const float*)d_in[3];
  const float* cov  = (const float*)d_in[4];
  float* ws  = (float*)d_ws;
  float* out = (float*)d_out;

  k_prep<<<196, 256, 0, stream>>>(wts, mu, cov, ws);
  k_mm<<<32 * KSPLIT, 256, 0, stream>>>(data, mask, ws);
  k_final<<<NB / 8, 256, 0, stream>>>(ws, out);
}

// Round 11
// 29.977 us; speedup vs baseline: 1.4980x; 1.1936x over previous
//
#include <hip/hip_runtime.h>
#include <math.h>

#define NB 2048
#define ND 784
#define NK 128
#define KP 3136            // 4*784: K = 4d+c, A slots {m*x^2, m*x, m, 0}
#define NSTEP 98           // KP/32 k-steps
#define KSPLIT 14          // K-chunks -> partials
#define SPK 7              // k-steps per chunk
#define MT 64              // rows per k_mm block (4 waves x 16 rows)
#define NHALF 2            // N-split: each wave does 4 nt = 64 cols

typedef __attribute__((ext_vector_type(8))) short short8;
typedef __attribute__((ext_vector_type(4))) float f32x4;

// ws float offsets:
#define OFF_LW   0
#define OFF_PART 128
#define N_PART   (KSPLIT * NB * NK)       // 3,670,016 floats (14.7 MB)
#define OFF_BH   (OFF_PART + N_PART)
#define N_B_F    (NSTEP * 8 * 64 * 4)     // 200,704 float slots per table
#define OFF_BL   (OFF_BH + N_B_F)
// total ~4.07M floats ~= 16.3 MB

__device__ inline ushort f2bf(float f) {   // round-to-nearest-even f32->bf16
  uint u = __float_as_uint(f);
  return (ushort)((u + 0x7FFFu + ((u >> 16) & 1u)) >> 16);
}

// B-prep + log w. Fragment fid = ks*8 + nt; lane l holds
// B[K = ks*32 + (l>>4)*8 + j][n = nt*16 + (l&15)], j=0..7, K = 4d+c:
// c==0 -> -1/2c, c==1 -> mu/c, c==2 -> -mu^2/2c - ln(c)/2, c==3 -> 0.
__global__ __launch_bounds__(256) void k_prep(
    const float* __restrict__ w, const float* __restrict__ mu,
    const float* __restrict__ cov, float* __restrict__ ws) {
  int tid = blockIdx.x * 256 + threadIdx.x;   // 0..50175
  if (tid < NK) ws[OFF_LW + tid] = logf(w[tid]);
  int l   = tid & 63;
  int fid = tid >> 6;          // 0..783
  int nt  = fid & 7;
  int ks  = fid >> 3;          // 0..97
  int n   = nt * 16 + (l & 15);
  int K0  = ks * 32 + ((l >> 4) << 3);
  ushort hi[8], lo[8];
#pragma unroll
  for (int j = 0; j < 8; j++) {
    int K = K0 + j;
    int d = K >> 2;
    int c = K & 3;
    float cv = cov[n * ND + d];
    float mv = mu[n * ND + d];
    float v = (c == 0) ? (-0.5f / cv)
            : (c == 1) ? (mv / cv)
            : (c == 2) ? (-mv * mv * 0.5f / cv - 0.5f * logf(cv))
                       : 0.f;
    ushort h = f2bf(v);
    hi[j] = h;
    lo[j] = f2bf(v - __uint_as_float(((uint)h) << 16));
  }
  uint4 vh, vl;
  vh.x = (uint)hi[0] | ((uint)hi[1] << 16);
  vh.y = (uint)hi[2] | ((uint)hi[3] << 16);
  vh.z = (uint)hi[4] | ((uint)hi[5] << 16);
  vh.w = (uint)hi[6] | ((uint)hi[7] << 16);
  vl.x = (uint)lo[0] | ((uint)lo[1] << 16);
  vl.y = (uint)lo[2] | ((uint)lo[3] << 16);
  vl.z = (uint)lo[4] | ((uint)lo[5] << 16);
  vl.w = (uint)lo[6] | ((uint)lo[7] << 16);
  ((uint4*)(ws + OFF_BH))[fid * 64 + l] = vh;
  ((uint4*)(ws + OFF_BL))[fid * 64 + l] = vl;
}

// GEMM, fused A-conversion, N-split: grid = 32 mt x NHALF x KSPLIT = 896
// blocks, 4 waves. Wave: 16 rows x 64 cols (nt = nh*4..nh*4+3) x SPK k-steps.
// Per k-step: ALL 8 B-fragment loads + x/m issued up front (one latency
// window), conversion VALU overlaps, then 12 MFMAs.
// acc layout (m89): col = lane&15, row = (lane>>4)*4 + reg.
__global__ __launch_bounds__(256, 3) void k_mm(
    const float* __restrict__ data, const float* __restrict__ mask,
    float* __restrict__ ws) {
  const short8* Bh = (const short8*)(ws + OFF_BH);
  const short8* Bl = (const short8*)(ws + OFF_BL);
  float* part = ws + OFF_PART;

  int bid = blockIdx.x;
  int mt  = bid / (NHALF * KSPLIT);
  int rem = bid % (NHALF * KSPLIT);
  int nh  = rem / KSPLIT;
  int kc  = rem % KSPLIT;
  int w   = threadIdx.x >> 6;
  int l   = threadIdx.x & 63;
  int r0  = mt * MT + w * 16;
  int rowA = r0 + (l & 15);
  int g2   = (l >> 4) << 1;     // dim offset within k-step: 0,2,4,6
  int n0   = nh * 4;            // first nt of this wave

  f32x4 acc[4];
#pragma unroll
  for (int i = 0; i < 4; i++) acc[i] = (f32x4){0.f, 0.f, 0.f, 0.f};

  const float* dp = data + (size_t)rowA * ND + g2;
  const float* mp = mask + (size_t)rowA * ND + g2;

#pragma unroll
  for (int s = 0; s < SPK; s++) {
    int ks = kc * SPK + s;
    // ---- batch all loads for this k-step (10 independent, one window)
    const short8* bh = Bh + ((size_t)(ks * 8) + n0) * 64 + l;
    const short8* bl = Bl + ((size_t)(ks * 8) + n0) * 64 + l;
    short8 b_h0 = bh[0], b_h1 = bh[64], b_h2 = bh[128], b_h3 = bh[192];
    short8 b_l0 = bl[0], b_l1 = bl[64], b_l2 = bl[128], b_l3 = bl[192];
    float2 x = *(const float2*)(dp + ks * 8);
    float2 m = *(const float2*)(mp + ks * 8);

    // ---- A conversion (overlaps the load window)
    float mx0 = m.x * x.x, mq0 = mx0 * x.x;
    float mx1 = m.y * x.y, mq1 = mx1 * x.y;
    ushort h_q0 = f2bf(mq0), h_x0 = f2bf(mx0);
    ushort h_q1 = f2bf(mq1), h_x1 = f2bf(mx1);
    ushort h_m0 = (ushort)(__float_as_uint(m.x) >> 16);  // exact: m in {0,1}
    ushort h_m1 = (ushort)(__float_as_uint(m.y) >> 16);
    float r_q0 = mq0 - __uint_as_float(((uint)h_q0) << 16);
    float r_x0 = mx0 - __uint_as_float(((uint)h_x0) << 16);
    float r_q1 = mq1 - __uint_as_float(((uint)h_q1) << 16);
    float r_x1 = mx1 - __uint_as_float(((uint)h_x1) << 16);

    short8 a_h, a_l;
    a_h[0] = (short)h_q0;       a_h[1] = (short)h_x0;
    a_h[2] = (short)h_m0;       a_h[3] = 0;
    a_h[4] = (short)h_q1;       a_h[5] = (short)h_x1;
    a_h[6] = (short)h_m1;       a_h[7] = 0;
    a_l[0] = (short)f2bf(r_q0); a_l[1] = (short)f2bf(r_x0);
    a_l[2] = 0;                 a_l[3] = 0;
    a_l[4] = (short)f2bf(r_q1); a_l[5] = (short)f2bf(r_x1);
    a_l[6] = 0;                 a_l[7] = 0;

    // ---- 12 MFMAs
    acc[0] = __builtin_amdgcn_mfma_f32_16x16x32_bf16(a_h, b_h0, acc[0], 0, 0, 0);
    acc[0] = __builtin_amdgcn_mfma_f32_16x16x32_bf16(a_h, b_l0, acc[0], 0, 0, 0);
    acc[0] = __builtin_amdgcn_mfma_f32_16x16x32_bf16(a_l, b_h0, acc[0], 0, 0, 0);
    acc[1] = __builtin_amdgcn_mfma_f32_16x16x32_bf16(a_h, b_h1, acc[1], 0, 0, 0);
    acc[1] = __builtin_amdgcn_mfma_f32_16x16x32_bf16(a_h, b_l1, acc[1], 0, 0, 0);
    acc[1] = __builtin_amdgcn_mfma_f32_16x16x32_bf16(a_l, b_h1, acc[1], 0, 0, 0);
    acc[2] = __builtin_amdgcn_mfma_f32_16x16x32_bf16(a_h, b_h2, acc[2], 0, 0, 0);
    acc[2] = __builtin_amdgcn_mfma_f32_16x16x32_bf16(a_h, b_l2, acc[2], 0, 0, 0);
    acc[2] = __builtin_amdgcn_mfma_f32_16x16x32_bf16(a_l, b_h2, acc[2], 0, 0, 0);
    acc[3] = __builtin_amdgcn_mfma_f32_16x16x32_bf16(a_h, b_h3, acc[3], 0, 0, 0);
    acc[3] = __builtin_amdgcn_mfma_f32_16x16x32_bf16(a_h, b_l3, acc[3], 0, 0, 0);
    acc[3] = __builtin_amdgcn_mfma_f32_16x16x32_bf16(a_l, b_h3, acc[3], 0, 0, 0);
  }

#pragma unroll
  for (int ntl = 0; ntl < 4; ntl++)
#pragma unroll
    for (int r = 0; r < 4; r++) {
      int grow = r0 + ((l >> 4) << 2) + r;
      part[((size_t)kc * NB + grow) * NK + (n0 + ntl) * 16 + (l & 15)] = acc[ntl][r];
    }
}

// 2 rows per wave, float4 per lane (k-quad). Reduce KSPLIT partials, +log w,
// NaN fix, LSE with the reference's per-term +1e-8 (4e-8 per lane), exp.
__global__ __launch_bounds__(256) void k_final(
    const float* __restrict__ ws, float* __restrict__ out) {
  const float4* lw4   = (const float4*)(ws + OFF_LW);
  const float4* part4 = (const float4*)(ws + OFF_PART);
  int lane = threadIdx.x & 63;
  int wv   = threadIdx.x >> 6;
  int half = lane >> 5;
  int lk   = lane & 31;
  int b = blockIdx.x * 8 + wv * 2 + half;

  float4 s = make_float4(0.f, 0.f, 0.f, 0.f);
#pragma unroll
  for (int sp = 0; sp < KSPLIT; sp++) {
    float4 v = part4[((size_t)sp * NB + b) * 32 + lk];
    s.x += v.x; s.y += v.y; s.z += v.z; s.w += v.w;
  }
  float4 lv = lw4[lk];
  s.x += lv.x; s.y += lv.y; s.z += lv.z; s.w += lv.w;
  if (isnan(s.x)) s.x = 0.f;
  if (isnan(s.y)) s.y = 0.f;
  if (isnan(s.z)) s.z = 0.f;
  if (isnan(s.w)) s.w = 0.f;

  float mx = fmaxf(fmaxf(s.x, s.y), fmaxf(s.z, s.w));
#pragma unroll
  for (int off = 16; off; off >>= 1) mx = fmaxf(mx, __shfl_xor(mx, off));
  float sum = expf(s.x - mx) + expf(s.y - mx) + expf(s.z - mx) + expf(s.w - mx) + 4e-8f;
#pragma unroll
  for (int off = 16; off; off >>= 1) sum += __shfl_xor(sum, off);
  float lse = logf(sum) + mx;
  float4 o = make_float4(expf(s.x - lse), expf(s.y - lse),
                         expf(s.z - lse), expf(s.w - lse));
  ((float4*)out)[(size_t)b * 32 + lk] = o;
}

extern "C" void kernel_launch(void* const* d_in, const int* in_sizes, int n_in,
                              void* d_out, int out_size, void* d_ws, size_t ws_size,
                              hipStream_t stream) {
  const float* data = (const float*)d_in[0];
  const float* mask = (const float*)d_in[1];
  const float* wts  = (const float*)d_in[2];
  const float* mu   = (const float*)d_in[3];
  const float* cov  = (const float*)d_in[4];
  float* ws  = (float*)d_ws;
  float* out = (float*)d_out;

  k_prep<<<196, 256, 0, stream>>>(wts, mu, cov, ws);
  k_mm<<<32 * NHALF * KSPLIT, 256, 0, stream>>>(data, mask, ws);
  k_final<<<NB / 8, 256, 0, stream>>>(ws, out);
}

// Round 12
// 29.679 us; speedup vs baseline: 1.5130x; 1.0100x over previous
//
#include <hip/hip_runtime.h>
#include <math.h>

#define NB 2048
#define ND 784
#define NK 128
#define KP 3136            // 4*784: K = 4d+c, A slots {m*x^2, m*x, m, 0}
#define NSTEP 98           // KP/32 k-steps
#define KSPLIT 14          // K-chunks -> partials
#define SPK 7              // k-steps per chunk
#define MT 64              // rows per k_mm block (4 waves x 16 rows)
#define NHALF 2            // N-split: each wave does 4 nt = 64 cols

typedef __attribute__((ext_vector_type(8))) short short8;
typedef __attribute__((ext_vector_type(4))) float f32x4;

// ws float offsets:
#define OFF_LW   0
#define OFF_PART 128
#define N_PART   (KSPLIT * NB * NK)       // 3,670,016 floats (14.7 MB)
#define OFF_BH   (OFF_PART + N_PART)
#define N_B_F    (NSTEP * 8 * 64 * 4)     // 200,704 float slots per table
#define OFF_BL   (OFF_BH + N_B_F)
// total ~4.07M floats ~= 16.3 MB

__device__ inline ushort f2bf(float f) {   // round-to-nearest-even f32->bf16
  uint u = __float_as_uint(f);
  return (ushort)((u + 0x7FFFu + ((u >> 16) & 1u)) >> 16);
}

// B-prep + log w. Fragment fid = ks*8 + nt; lane l holds
// B[K = ks*32 + (l>>4)*8 + j][n = nt*16 + (l&15)], j=0..7, K = 4d+c:
// c==0 -> -1/2c, c==1 -> mu/c, c==2 -> -mu^2/2c - ln(c)/2, c==3 -> 0.
__global__ __launch_bounds__(256) void k_prep(
    const float* __restrict__ w, const float* __restrict__ mu,
    const float* __restrict__ cov, float* __restrict__ ws) {
  int tid = blockIdx.x * 256 + threadIdx.x;   // 0..50175
  if (tid < NK) ws[OFF_LW + tid] = logf(w[tid]);
  int l   = tid & 63;
  int fid = tid >> 6;          // 0..783
  int nt  = fid & 7;
  int ks  = fid >> 3;          // 0..97
  int n   = nt * 16 + (l & 15);
  int K0  = ks * 32 + ((l >> 4) << 3);
  ushort hi[8], lo[8];
#pragma unroll
  for (int j = 0; j < 8; j++) {
    int K = K0 + j;
    int d = K >> 2;
    int c = K & 3;
    float cv = cov[n * ND + d];
    float mv = mu[n * ND + d];
    float v = (c == 0) ? (-0.5f / cv)
            : (c == 1) ? (mv / cv)
            : (c == 2) ? (-mv * mv * 0.5f / cv - 0.5f * logf(cv))
                       : 0.f;
    ushort h = f2bf(v);
    hi[j] = h;
    lo[j] = f2bf(v - __uint_as_float(((uint)h) << 16));
  }
  uint4 vh, vl;
  vh.x = (uint)hi[0] | ((uint)hi[1] << 16);
  vh.y = (uint)hi[2] | ((uint)hi[3] << 16);
  vh.z = (uint)hi[4] | ((uint)hi[5] << 16);
  vh.w = (uint)hi[6] | ((uint)hi[7] << 16);
  vl.x = (uint)lo[0] | ((uint)lo[1] << 16);
  vl.y = (uint)lo[2] | ((uint)lo[3] << 16);
  vl.z = (uint)lo[4] | ((uint)lo[5] << 16);
  vl.w = (uint)lo[6] | ((uint)lo[7] << 16);
  ((uint4*)(ws + OFF_BH))[fid * 64 + l] = vh;
  ((uint4*)(ws + OFF_BL))[fid * 64 + l] = vl;
}

// GEMM, fused A-conversion, N-split, DEPTH-2 SOFTWARE PIPELINE:
// grid = 32 mt x NHALF x KSPLIT = 896 blocks, 4 waves.
// Wave: 16 rows x 64 cols (nt = nh*4..) x SPK k-steps. While step s computes,
// step s+1's 8 B-fragments + x/m are already in flight (double-buffered regs,
// all indices compile-time after full unroll).
// acc layout (m89): col = lane&15, row = (lane>>4)*4 + reg.
__global__ __launch_bounds__(256, 3) void k_mm(
    const float* __restrict__ data, const float* __restrict__ mask,
    float* __restrict__ ws) {
  const short8* Bh = (const short8*)(ws + OFF_BH);
  const short8* Bl = (const short8*)(ws + OFF_BL);
  float* part = ws + OFF_PART;

  int bid = blockIdx.x;
  int mt  = bid / (NHALF * KSPLIT);
  int rem = bid % (NHALF * KSPLIT);
  int nh  = rem / KSPLIT;
  int kc  = rem % KSPLIT;
  int w   = threadIdx.x >> 6;
  int l   = threadIdx.x & 63;
  int r0  = mt * MT + w * 16;
  int rowA = r0 + (l & 15);
  int g2   = (l >> 4) << 1;     // dim offset within k-step: 0,2,4,6
  int n0   = nh * 4;            // first nt of this wave

  f32x4 acc[4];
#pragma unroll
  for (int i = 0; i < 4; i++) acc[i] = (f32x4){0.f, 0.f, 0.f, 0.f};

  const float* dp = data + (size_t)rowA * ND + g2;
  const float* mp = mask + (size_t)rowA * ND + g2;

  short8 Bhb[2][4], Blb[2][4];
  float2 xb[2], mb[2];

  auto loadstep = [&](int s, int buf) {
    int ks = kc * SPK + s;
    const short8* bh = Bh + ((size_t)(ks * 8) + n0) * 64 + l;
    const short8* bl = Bl + ((size_t)(ks * 8) + n0) * 64 + l;
    Bhb[buf][0] = bh[0];  Bhb[buf][1] = bh[64];
    Bhb[buf][2] = bh[128]; Bhb[buf][3] = bh[192];
    Blb[buf][0] = bl[0];  Blb[buf][1] = bl[64];
    Blb[buf][2] = bl[128]; Blb[buf][3] = bl[192];
    xb[buf] = *(const float2*)(dp + ks * 8);
    mb[buf] = *(const float2*)(mp + ks * 8);
  };

  loadstep(0, 0);

#pragma unroll
  for (int s = 0; s < SPK; s++) {
    const int cur = s & 1;
    const int nxt = cur ^ 1;
    if (s + 1 < SPK) loadstep(s + 1, nxt);   // in flight during this step

    float2 x = xb[cur], m = mb[cur];
    float mx0 = m.x * x.x, mq0 = mx0 * x.x;
    float mx1 = m.y * x.y, mq1 = mx1 * x.y;
    ushort h_q0 = f2bf(mq0), h_x0 = f2bf(mx0);
    ushort h_q1 = f2bf(mq1), h_x1 = f2bf(mx1);
    ushort h_m0 = (ushort)(__float_as_uint(m.x) >> 16);  // exact: m in {0,1}
    ushort h_m1 = (ushort)(__float_as_uint(m.y) >> 16);
    float r_q0 = mq0 - __uint_as_float(((uint)h_q0) << 16);
    float r_x0 = mx0 - __uint_as_float(((uint)h_x0) << 16);
    float r_q1 = mq1 - __uint_as_float(((uint)h_q1) << 16);
    float r_x1 = mx1 - __uint_as_float(((uint)h_x1) << 16);

    short8 a_h, a_l;
    a_h[0] = (short)h_q0;       a_h[1] = (short)h_x0;
    a_h[2] = (short)h_m0;       a_h[3] = 0;
    a_h[4] = (short)h_q1;       a_h[5] = (short)h_x1;
    a_h[6] = (short)h_m1;       a_h[7] = 0;
    a_l[0] = (short)f2bf(r_q0); a_l[1] = (short)f2bf(r_x0);
    a_l[2] = 0;                 a_l[3] = 0;
    a_l[4] = (short)f2bf(r_q1); a_l[5] = (short)f2bf(r_x1);
    a_l[6] = 0;                 a_l[7] = 0;

    acc[0] = __builtin_amdgcn_mfma_f32_16x16x32_bf16(a_h, Bhb[cur][0], acc[0], 0, 0, 0);
    acc[0] = __builtin_amdgcn_mfma_f32_16x16x32_bf16(a_h, Blb[cur][0], acc[0], 0, 0, 0);
    acc[0] = __builtin_amdgcn_mfma_f32_16x16x32_bf16(a_l, Bhb[cur][0], acc[0], 0, 0, 0);
    acc[1] = __builtin_amdgcn_mfma_f32_16x16x32_bf16(a_h, Bhb[cur][1], acc[1], 0, 0, 0);
    acc[1] = __builtin_amdgcn_mfma_f32_16x16x32_bf16(a_h, Blb[cur][1], acc[1], 0, 0, 0);
    acc[1] = __builtin_amdgcn_mfma_f32_16x16x32_bf16(a_l, Bhb[cur][1], acc[1], 0, 0, 0);
    acc[2] = __builtin_amdgcn_mfma_f32_16x16x32_bf16(a_h, Bhb[cur][2], acc[2], 0, 0, 0);
    acc[2] = __builtin_amdgcn_mfma_f32_16x16x32_bf16(a_h, Blb[cur][2], acc[2], 0, 0, 0);
    acc[2] = __builtin_amdgcn_mfma_f32_16x16x32_bf16(a_l, Bhb[cur][2], acc[2], 0, 0, 0);
    acc[3] = __builtin_amdgcn_mfma_f32_16x16x32_bf16(a_h, Bhb[cur][3], acc[3], 0, 0, 0);
    acc[3] = __builtin_amdgcn_mfma_f32_16x16x32_bf16(a_h, Blb[cur][3], acc[3], 0, 0, 0);
    acc[3] = __builtin_amdgcn_mfma_f32_16x16x32_bf16(a_l, Bhb[cur][3], acc[3], 0, 0, 0);
  }

#pragma unroll
  for (int ntl = 0; ntl < 4; ntl++)
#pragma unroll
    for (int r = 0; r < 4; r++) {
      int grow = r0 + ((l >> 4) << 2) + r;
      part[((size_t)kc * NB + grow) * NK + (n0 + ntl) * 16 + (l & 15)] = acc[ntl][r];
    }
}

// 2 rows per wave, float4 per lane (k-quad). Reduce KSPLIT partials, +log w,
// NaN fix, LSE with the reference's per-term +1e-8 (4e-8 per lane), exp.
__global__ __launch_bounds__(256) void k_final(
    const float* __restrict__ ws, float* __restrict__ out) {
  const float4* lw4   = (const float4*)(ws + OFF_LW);
  const float4* part4 = (const float4*)(ws + OFF_PART);
  int lane = threadIdx.x & 63;
  int wv   = threadIdx.x >> 6;
  int half = lane >> 5;
  int lk   = lane & 31;
  int b = blockIdx.x * 8 + wv * 2 + half;

  float4 s = make_float4(0.f, 0.f, 0.f, 0.f);
#pragma unroll
  for (int sp = 0; sp < KSPLIT; sp++) {
    float4 v = part4[((size_t)sp * NB + b) * 32 + lk];
    s.x += v.x; s.y += v.y; s.z += v.z; s.w += v.w;
  }
  float4 lv = lw4[lk];
  s.x += lv.x; s.y += lv.y; s.z += lv.z; s.w += lv.w;
  if (isnan(s.x)) s.x = 0.f;
  if (isnan(s.y)) s.y = 0.f;
  if (isnan(s.z)) s.z = 0.f;
  if (isnan(s.w)) s.w = 0.f;

  float mx = fmaxf(fmaxf(s.x, s.y), fmaxf(s.z, s.w));
#pragma unroll
  for (int off = 16; off; off >>= 1) mx = fmaxf(mx, __shfl_xor(mx, off));
  float sum = expf(s.x - mx) + expf(s.y - mx) + expf(s.z - mx) + expf(s.w - mx) + 4e-8f;
#pragma unroll
  for (int off = 16; off; off >>= 1) sum += __shfl_xor(sum, off);
  float lse = logf(sum) + mx;
  float4 o = make_float4(expf(s.x - lse), expf(s.y - lse),
                         expf(s.z - lse), expf(s.w - lse));
  ((float4*)out)[(size_t)b * 32 + lk] = o;
}

extern "C" void kernel_launch(void* const* d_in, const int* in_sizes, int n_in,
                              void* d_out, int out_size, void* d_ws, size_t ws_size,
                              hipStream_t stream) {
  const float* data = (const float*)d_in[0];
  const float* mask = (const float*)d_in[1];
  const float* wts  = (const float*)d_in[2];
  const float* mu   = (const float*)d_in[3];
  const float* cov  = (const float*)d_in[4];
  float* ws  = (float*)d_ws;
  float* out = (float*)d_out;

  k_prep<<<196, 256, 0, stream>>>(wts, mu, cov, ws);
  k_mm<<<32 * NHALF * KSPLIT, 256, 0, stream>>>(data, mask, ws);
  k_final<<<NB / 8, 256, 0, stream>>>(ws, out);
}